// Round 13
// baseline (78.359 us; speedup 1.0000x reference)
//
#include <hip/hip_runtime.h>

typedef __bf16 bf16x8 __attribute__((ext_vector_type(8)));
typedef float f32x4 __attribute__((ext_vector_type(4)));
typedef short s16x8 __attribute__((ext_vector_type(8)));
typedef short s16x4 __attribute__((ext_vector_type(4)));
typedef unsigned short u16;
typedef unsigned int u32;
typedef unsigned long long u64;

#define S_LEN 4096
#define DMODEL 1024
#define NH 16
#define HD 64

static __device__ __forceinline__ u16 f2bf(float f) {
  union { float f; u32 u; } a; a.f = f;
  u32 r = (a.u + 0x7fffu + ((a.u >> 16) & 1u)) >> 16;
  return (u16)r;
}

static __device__ __forceinline__ f32x4 mfma16(bf16x8 a, bf16x8 b, f32x4 c) {
  return __builtin_amdgcn_mfma_f32_16x16x32_bf16(a, b, c, 0, 0, 0);
}

static __device__ __forceinline__ f32x4 mfma16x16(s16x4 a, s16x4 b, f32x4 c) {
#if __has_builtin(__builtin_amdgcn_mfma_f32_16x16x16bf16_1k)
  return __builtin_amdgcn_mfma_f32_16x16x16bf16_1k(a, b, c, 0, 0, 0);
#else
  asm("v_mfma_f32_16x16x16_bf16 %0, %1, %2, %0" : "+v"(c) : "v"(a), "v"(b));
  return c;
#endif
}

static __device__ __forceinline__ void gload16(const void* g, void* l) {
  __builtin_amdgcn_global_load_lds((const __attribute__((address_space(1))) u32*)g,
                                   (__attribute__((address_space(3))) u32*)l, 16, 0, 0);
}

// counted-vmcnt barrier pair: loads issued for the NEXT tile stay in flight
// across the barrier (only the CURRENT tile's loads are waited on).
#define WAIT_VM(N) asm volatile("s_waitcnt vmcnt(" #N ")" ::: "memory")
static __device__ __forceinline__ void sbar() { __builtin_amdgcn_s_barrier(); }
static __device__ __forceinline__ void spin() { __builtin_amdgcn_sched_barrier(0); }

// bijective chunked XCD swizzle (requires nwg % 8 == 0)
static __device__ __forceinline__ int xcd_swz(int id, int nwg) {
  return (id & 7) * (nwg >> 3) + (id >> 3);
}

// ---------------- fused prep: cast + 4 weight transposes + spec scan ----------------
__global__ __launch_bounds__(256)
void prep_kernel(const float* __restrict__ hidden, const float* __restrict__ Wq,
                 const float* __restrict__ Wk, const float* __restrict__ Wv,
                 const float* __restrict__ Wo, const int* __restrict__ spec,
                 const int* __restrict__ eosi,
                 u16* __restrict__ hbf, u16* __restrict__ wqkvT, u16* __restrict__ woT,
                 u64* __restrict__ spb, int* __restrict__ srank, int4* __restrict__ qmeta) {
  __shared__ float ftile[32][33];
  __shared__ u64 smask[64];
  __shared__ int scnt_s[64];
  __shared__ int spref[64];

  const int bx = (int)blockIdx.x;
  const int t = (int)threadIdx.x;

  if (bx < 4096) {  // cast
    const int i = (bx * 256 + t) * 4;
    const float4 v = *(const float4*)(hidden + i);
    uint2 o;
    o.x = (u32)f2bf(v.x) | ((u32)f2bf(v.y) << 16);
    o.y = (u32)f2bf(v.z) | ((u32)f2bf(v.w) << 16);
    *(uint2*)(hbf + i) = o;
    return;
  }
  if (bx < 6656) {  // weight transposes
    const float* W; u16* WT; int N, loc, nbx;
    if (bx < 5120)      { W = Wq; WT = wqkvT;               N = 1024; loc = bx - 4096; nbx = 32; }
    else if (bx < 5376) { W = Wk; WT = wqkvT + 1024 * 1024; N = 256;  loc = bx - 5120; nbx = 8; }
    else if (bx < 5632) { W = Wv; WT = wqkvT + 1280 * 1024; N = 256;  loc = bx - 5376; nbx = 8; }
    else                { W = Wo; WT = woT;                 N = 1024; loc = bx - 5632; nbx = 32; }
    const int n0 = (loc % nbx) * 32, k0 = (loc / nbx) * 32;
    const int tx = t & 31, ty = t >> 5;
#pragma unroll
    for (int i = 0; i < 4; ++i)
      ftile[ty + 8 * i][tx] = W[(size_t)(k0 + ty + 8 * i) * N + n0 + tx];
    __syncthreads();
#pragma unroll
    for (int i = 0; i < 4; ++i)
      WT[(size_t)(n0 + ty + 8 * i) * 1024 + k0 + tx] = f2bf(ftile[tx][ty + 8 * i]);
    return;
  }
  // spec scan block: bitmasks, per-token spec rank, per-qtile metadata
  const int wv = t >> 6, l = t & 63;
#pragma unroll
  for (int i = 0; i < 16; ++i) {
    const int b = wv * 16 + i;
    const u64 m = __ballot(spec[b * 64 + l] != 0);
    if (l == 0) { smask[b] = m; scnt_s[b] = __popcll(m); }
  }
  __syncthreads();
  if (wv == 0) {
    const int v = scnt_s[l];
    int inc = v;
#pragma unroll
    for (int d = 1; d < 64; d <<= 1) {
      const int o = __shfl_up(inc, d);
      if (l >= d) inc += o;
    }
    spref[l] = inc - v;  // exclusive prefix
    spb[l] = smask[l];
  }
  __syncthreads();
#pragma unroll
  for (int i = 0; i < 16; ++i) {
    const int b = wv * 16 + i;
    const u64 m = smask[b];
    srank[b * 64 + l] = ((m >> l) & 1ull)
        ? spref[b] + __popcll(m & ((1ull << l) - 1ull)) : -1;
  }
  if (t < 64) {
    const int e = eosi[t * 64];
    const int tlo = e >> 6;
    const int nsp = spref[tlo];
    const int nspt = (nsp + 63) >> 6;
    qmeta[t] = make_int4(tlo, nspt, nspt + (t - tlo + 1), nsp);
  }
}

// ---------------- 128x64 MFMA GEMM, BK=64, dbuf + counted-vmcnt (r8 structure) --------
// MODE 0: C fp32 out.  MODE 1: QKV, RoPE fused; K->Kb(+Kg spec), V->Vtg(+Vgt spec).
template <int MODE>
__global__ __launch_bounds__(256, 3)
void gemm128(const u16* __restrict__ A, const u16* __restrict__ BT,
             const float* __restrict__ cosp, const float* __restrict__ sinp,
             const int* __restrict__ srank,
             u16* __restrict__ Qb, u16* __restrict__ Kb, u16* __restrict__ Vtg,
             u16* __restrict__ Kg, u16* __restrict__ Vgt,
             float* __restrict__ Cf) {
  __shared__ __align__(16) u16 As[2][128 * 64];
  __shared__ __align__(16) u16 Bs[2][64 * 64];
  const int t = (int)threadIdx.x;
  const int w = t >> 6;
  const int lane = t & 63;
  const int lr = lane & 15, lg = lane >> 4;

  const int nx = (int)gridDim.x;
  const int nwg = nx * (int)gridDim.y;
  const int id = xcd_swz((int)blockIdx.x + (int)blockIdx.y * nx, nwg);
  const int m0 = (id / nx) * 128;
  const int n0 = (id % nx) * 64;
  const int wm = w * 32;

  f32x4 acc[2][4] = {};

  const int srow = t >> 3;   // 0..31 (per 32-row pass)
  const int sp = t & 7;      // dest 16B chunk within 128B row

  // staging: linear LDS dest (lane-ordered), source chunk pre-swizzled p^(row&7)
  auto STAGE = [&](int buf, int k0) {  // 6 gload16 per thread
#pragma unroll
    for (int i = 0; i < 4; ++i) {
      const int j = i * 32 + srow;
      gload16(A + (size_t)(m0 + j) * 1024 + k0 + ((sp ^ (j & 7)) * 8),
              &As[buf][i * 2048 + t * 8]);
    }
#pragma unroll
    for (int i = 0; i < 2; ++i) {
      const int j = i * 32 + srow;
      gload16(BT + (size_t)(n0 + j) * 1024 + k0 + ((sp ^ (j & 7)) * 8),
              &Bs[buf][i * 2048 + t * 8]);
    }
  };

  STAGE(0, 0);

  for (int it = 0; it < 16; ++it) {
    const int cur = it & 1;
    if (it < 15) {
      STAGE(cur ^ 1, (it + 1) * 64);  // 6 next-tile loads stay in flight
      WAIT_VM(6);                     // only current tile's 6 loads complete
    } else {
      WAIT_VM(0);
    }
    spin();
    sbar();                           // raw barrier: no vmcnt(0) drain
#pragma unroll
    for (int c = 0; c < 2; ++c) {     // k ascending: bit-identical accumulation
      bf16x8 af[2], bg[4];
#pragma unroll
      for (int mi = 0; mi < 2; ++mi) {
        const int row = wm + mi * 16 + lr;
        af[mi] = *(const bf16x8*)&As[cur][row * 64 + (((c * 4 + lg) ^ (row & 7)) * 8)];
      }
#pragma unroll
      for (int ni = 0; ni < 4; ++ni) {
        const int row = ni * 16 + lr;
        bg[ni] = *(const bf16x8*)&Bs[cur][row * 64 + (((c * 4 + lg) ^ (row & 7)) * 8)];
      }
#pragma unroll
      for (int mi = 0; mi < 2; ++mi)
#pragma unroll
        for (int ni = 0; ni < 4; ++ni)
          acc[mi][ni] = mfma16(af[mi], bg[ni], acc[mi][ni]);
    }
    spin();
    sbar();                           // protect cur buffer before next STAGE overwrites
  }

  if (MODE == 0) {
#pragma unroll
    for (int mi = 0; mi < 2; ++mi)
#pragma unroll
      for (int r = 0; r < 4; ++r) {
        const int m = m0 + wm + mi * 16 + lg * 4 + r;
#pragma unroll
        for (int ni = 0; ni < 4; ++ni)
          Cf[(size_t)m * 1024 + n0 + ni * 16 + lr] = acc[mi][ni][r];
      }
  } else if (n0 < 1280) {
    // RoPE (Q or K): pair (d, d+32) = (acc[mi][ni], acc[mi][ni+2])
#pragma unroll
    for (int mi = 0; mi < 2; ++mi)
#pragma unroll
      for (int r = 0; r < 4; ++r) {
        const int m = m0 + wm + mi * 16 + lg * 4 + r;
        const float* cr = cosp + (size_t)m * 64;
        const float* sr = sinp + (size_t)m * 64;
        float o[4];
#pragma unroll
        for (int ni = 0; ni < 2; ++ni) {
          const int d1 = ni * 16 + lr, d2 = d1 + 32;
          const float x = acc[mi][ni][r], y = acc[mi][ni + 2][r];
          o[ni]     = x * cr[d1] - y * sr[d1];
          o[ni + 2] = y * cr[d2] + x * sr[d2];
        }
        if (n0 < 1024) {
          u16* dst = Qb + (size_t)m * 1024 + n0;
#pragma unroll
          for (int ni = 0; ni < 4; ++ni) dst[ni * 16 + lr] = f2bf(o[ni]);
        } else {
          u16 hv[4];
#pragma unroll
          for (int ni = 0; ni < 4; ++ni) hv[ni] = f2bf(o[ni]);
          u16* dst = Kb + (size_t)m * 256 + (n0 - 1024);
          const int sw = (m & 7) << 3;
#pragma unroll
          for (int ni = 0; ni < 4; ++ni) dst[(ni * 16 + lr) ^ sw] = hv[ni];
          const int rk = srank[m];      // fused spec-K gather (same bits as pack did)
          if (rk >= 0) {
            u16* dg = Kg + (size_t)rk * 256 + (n0 - 1024);
            const int swg = (rk & 7) << 3;
#pragma unroll
            for (int ni = 0; ni < 4; ++ni) dg[(ni * 16 + lr) ^ swg] = hv[ni];
          }
        }
      }
  } else {
    // V: transposed + chunk-swizzled into Vtg[kvh*64+d][s]; spec cols also into Vgt
    const int kvh = (n0 - 1280) >> 6;
    int rks[2][4];
#pragma unroll
    for (int mi = 0; mi < 2; ++mi)
#pragma unroll
      for (int r = 0; r < 4; ++r)
        rks[mi][r] = srank[m0 + wm + mi * 16 + lg * 4 + r];
#pragma unroll
    for (int ni = 0; ni < 4; ++ni) {
      const int d = ni * 16 + lr;
      u16* vrow = Vtg + (size_t)(kvh * 64 + d) * 4096;
      u16* grow_ = Vgt + (size_t)(kvh * 64 + d) * 4096;
      const int xd = (d & 7) << 3;
#pragma unroll
      for (int mi = 0; mi < 2; ++mi) {
        const int sb = m0 + wm + mi * 16 + lg * 4;
        const int os = (sb & ~63) | ((sb & 63) ^ xd);
        u16 bv[4];
#pragma unroll
        for (int r = 0; r < 4; ++r) bv[r] = f2bf(acc[mi][ni][r]);
        uint2 pkv;
        pkv.x = (u32)bv[0] | ((u32)bv[1] << 16);
        pkv.y = (u32)bv[2] | ((u32)bv[3] << 16);
        *(uint2*)(vrow + os) = pkv;
#pragma unroll
        for (int r = 0; r < 4; ++r) {   // fused spec-V gather (~5% of rows)
          const int j = rks[mi][r];
          if (j >= 0) grow_[(j & ~63) + ((j & 63) ^ xd)] = bv[r];
        }
      }
    }
  }
}

// ------- flash attention, sentence-sparse, counted-vmcnt, 2 heads (1 KV stage) -------
// grid (32, 16) = 512 blocks XCD-swizzled; block = (q-tile, head-pair of same kvh)
__global__ __launch_bounds__(256, 4)
void attn_kernel(const u16* __restrict__ Qb, const u16* __restrict__ Kb,
                 const u16* __restrict__ Vtg, const u16* __restrict__ Kg,
                 const u16* __restrict__ Vgt, const u64* __restrict__ spb,
                 const int* __restrict__ eosi, const int4* __restrict__ qmeta,
                 u16* __restrict__ Ob) {
  __shared__ __align__(16) u16 lds[2][2][4096];

  const int id = xcd_swz((int)blockIdx.x + (int)blockIdx.y * 32, 512);
  const int qt = 63 - (id & 63);
  const int hp = id >> 6;          // head pair 0..7
  const int h0 = hp * 2;           // heads h0, h0+1 share kvh = h0>>2 = hp>>1
  const int kvh = hp >> 1;
  const int t = (int)threadIdx.x;
  const int w = t >> 6;
  const int lane = t & 63;
  const int lr = lane & 15, lg = lane >> 4;
  const int q0 = qt * 64;
  const int q = q0 + w * 16 + lr;
  const int swl = (lr & 7) << 3;

  const int4 qm = qmeta[qt];       // {tile_lo, nspt, nit, nsp}
  const int tile_lo = qm.x;
  const int nit = qm.z;
  const int nsp = qm.w;
  const int nloc = qt - tile_lo + 1;

  bf16x8 aq[2][2];
#pragma unroll
  for (int hd = 0; hd < 2; ++hd) {
    const u16* qp = Qb + (size_t)q * 1024 + (h0 + hd) * 64 + lg * 8;
    aq[hd][0] = *(const bf16x8*)qp;
    aq[hd][1] = *(const bf16x8*)(qp + 32);
  }
  const int eos_q = eosi[q];       // head-independent

  f32x4 acc[2][4] = {};
  float mrow[2] = {-3.0e38f, -3.0e38f};
  float lrow[2] = {0.0f, 0.0f};

  const int grow = t >> 3;
  const int gcol = (t & 7) * 8;

  auto STAGE = [&](int buf, int it) {  // 4 gload16 per thread (shared by both heads)
    const u16 *kp, *vp;
    if (it < nloc) {
      const int kbase = (tile_lo + it) * 64;
      kp = Kb + (size_t)kbase * 256 + kvh * 64;
      vp = Vtg + (size_t)(kvh * 64) * 4096 + kbase;
    } else {
      const int jb = (it - nloc) * 64;
      kp = Kg + (size_t)jb * 256 + kvh * 64;
      vp = Vgt + (size_t)(kvh * 64) * 4096 + jb;
    }
#pragma unroll
    for (int i = 0; i < 2; ++i) {
      gload16(kp + (size_t)(i * 32 + grow) * 256 + gcol, &lds[buf][0][i * 2048 + t * 8]);
      gload16(vp + (size_t)(i * 32 + grow) * 4096 + gcol, &lds[buf][1][i * 2048 + t * 8]);
    }
  };

  STAGE(0, 0);

  for (int it = 0; it < nit; ++it) {
    if (it + 1 < nit) {
      STAGE((it + 1) & 1, it + 1);   // next-tile loads stay in flight
      WAIT_VM(4);
    } else {
      WAIT_VM(0);
    }
    spin();
    sbar();
    const u16* Kl = &lds[it & 1][0][0];
    const u16* Vl = &lds[it & 1][1][0];

    // mask (head-independent, computed once)
    u64 allowed;
    if (it < nloc) {
      const int kbase = (tile_lo + it) * 64;
      const u64 spec = spb[tile_lo + it];
      const int dq = q - kbase;
      const u64 causal = (dq >= 63) ? ~0ull : ((2ull << dq) - 1ull);
      const int de = eos_q - kbase;
      const u64 ge = (de <= 0) ? ~0ull : (de >= 64 ? 0ull : (~0ull << de));
      allowed = causal & (ge | spec);
    } else {
      const int rem = nsp - (it - nloc) * 64;
      allowed = (rem >= 64) ? ~0ull : ((1ull << rem) - 1ull);
    }

#pragma unroll
    for (int hd = 0; hd < 2; ++hd) {
      f32x4 st[4];
#pragma unroll
      for (int kt = 0; kt < 4; ++kt) {
        f32x4 s = {};
#pragma unroll
        for (int c = 0; c < 2; ++c) {
          bf16x8 ak = *(const bf16x8*)(Kl + (kt * 16 + lr) * 64 + ((c * 32 + lg * 8) ^ swl));
          s = mfma16(ak, aq[hd][c], s);
        }
        st[kt] = s;
      }

      float xs[16];
      float tmax = -3.0e38f;
#pragma unroll
      for (int kt = 0; kt < 4; ++kt) {
        const u32 bits = (u32)(allowed >> (kt * 16 + lg * 4)) & 0xFu;
#pragma unroll
        for (int r = 0; r < 4; ++r) {
          const float x = ((bits >> r) & 1u) ? st[kt][r] * 0.18033688011112042f : -3.0e38f;
          xs[kt * 4 + r] = x;
          tmax = fmaxf(tmax, x);
        }
      }
      tmax = fmaxf(tmax, __shfl_xor(tmax, 16));
      tmax = fmaxf(tmax, __shfl_xor(tmax, 32));
      const float mn = fmaxf(mrow[hd], tmax);
      const float resc = exp2f(mrow[hd] - mn);
      mrow[hd] = mn;

      float rs = 0.0f;
      u32 pk[8];
#pragma unroll
      for (int i = 0; i < 16; i += 2) {
        const float p0 = exp2f(xs[i] - mn);
        const float p1 = exp2f(xs[i + 1] - mn);
        rs += p0 + p1;
        pk[i >> 1] = (u32)f2bf(p0) | ((u32)f2bf(p1) << 16);
      }
      rs += __shfl_xor(rs, 16);
      rs += __shfl_xor(rs, 32);
      lrow[hd] = lrow[hd] * resc + rs;

#pragma unroll
      for (int dt = 0; dt < 4; ++dt)
#pragma unroll
        for (int r = 0; r < 4; ++r) acc[hd][dt][r] *= resc;

#pragma unroll
      for (int kt = 0; kt < 4; ++kt) {
        union { u32 u[2]; s16x4 v; } cv;
        cv.u[0] = pk[kt * 2]; cv.u[1] = pk[kt * 2 + 1];
        const int vo = (kt * 16 + lg * 4) ^ swl;
#pragma unroll
        for (int dt = 0; dt < 4; ++dt) {
          s16x4 av = *(const s16x4*)(Vl + (dt * 16 + lr) * 64 + vo);
          acc[hd][dt] = mfma16x16(av, cv.v, acc[hd][dt]);
        }
      }
    }
    spin();
    sbar();
  }

#pragma unroll
  for (int hd = 0; hd < 2; ++hd) {
    const float inv = 1.0f / lrow[hd];
#pragma unroll
    for (int dt = 0; dt < 4; ++dt) {
      const u32 w0 = (u32)f2bf(acc[hd][dt][0] * inv) | ((u32)f2bf(acc[hd][dt][1] * inv) << 16);
      const u32 w1 = (u32)f2bf(acc[hd][dt][2] * inv) | ((u32)f2bf(acc[hd][dt][3] * inv) << 16);
      u32* dst = (u32*)(Ob + (size_t)q * 1024 + (h0 + hd) * 64 + dt * 16 + lg * 4);
      dst[0] = w0; dst[1] = w1;
    }
  }
}

// ---------------- launch (4 kernels) ----------------
extern "C" void kernel_launch(void* const* d_in, const int* in_sizes, int n_in,
                              void* d_out, int out_size, void* d_ws, size_t ws_size,
                              hipStream_t stream) {
  (void)in_sizes; (void)n_in; (void)out_size; (void)ws_size;
  const float* hidden = (const float*)d_in[0];
  const float* cosp   = (const float*)d_in[1];
  const float* sinp   = (const float*)d_in[2];
  const float* Wq     = (const float*)d_in[3];
  const float* Wk     = (const float*)d_in[4];
  const float* Wv     = (const float*)d_in[5];
  const float* Wo     = (const float*)d_in[6];
  const int* spec     = (const int*)d_in[7];
  const int* eosi     = (const int*)d_in[8];
  float* out = (float*)d_out;

  u16* ws = (u16*)d_ws;
  u16* hbf   = ws;                       // 4096*1024
  u16* wqkvT = hbf + 4194304;            // 1536*1024
  u16* woT   = wqkvT + 1572864;          // 1024*1024
  u16* Qb    = woT + 1048576;            // 4096*1024
  u16* Kb    = Qb + 4194304;             // 4096*256 (chunk-swizzled by row)
  u16* Vtg   = Kb + 1048576;             // 4*64*4096 transposed V (written by gemm<1>)
  u16* Ob    = Vtg + 1048576;            // 4096*1024
  u16* tail  = Ob + 4194304;             // spec metadata
  u64* spb   = (u64*)tail;               // 64 x u64           (tail + 0)
  int* srank = (int*)(tail + 256);       // 4096 int           (tail + 256)
  int4* qmeta = (int4*)(tail + 8448);    // 64 x int4          (tail + 8448)
  u16* Kg    = tail + 8960;              // 4096*256 packed special K (gemm<1>-fused)
  u16* Vgt   = Kg + 1048576;             // 4*64*4096 packed special V^T (gemm<1>-fused)

  prep_kernel<<<dim3(6657), dim3(256), 0, stream>>>(hidden, Wq, Wk, Wv, Wo, spec, eosi,
                                                    hbf, wqkvT, woT, spb, srank, qmeta);
  gemm128<1><<<dim3(24, 32), dim3(256), 0, stream>>>(hbf, wqkvT, cosp, sinp, srank,
                                                     Qb, Kb, Vtg, Kg, Vgt, nullptr);
  attn_kernel<<<dim3(32, 16), dim3(256), 0, stream>>>(Qb, Kb, Vtg, Kg, Vgt, spb,
                                                      eosi, qmeta, Ob);
  gemm128<0><<<dim3(16, 32), dim3(256), 0, stream>>>(Ob, woT, nullptr, nullptr, nullptr,
                                                     nullptr, nullptr, nullptr, nullptr,
                                                     nullptr, out);
}

// Round 14
// 74.851 us; speedup vs baseline: 1.0469x; 1.0469x over previous
//
#include <hip/hip_runtime.h>

typedef __bf16 bf16x8 __attribute__((ext_vector_type(8)));
typedef float f32x4 __attribute__((ext_vector_type(4)));
typedef short s16x8 __attribute__((ext_vector_type(8)));
typedef short s16x4 __attribute__((ext_vector_type(4)));
typedef unsigned short u16;
typedef unsigned int u32;
typedef unsigned long long u64;

#define S_LEN 4096
#define DMODEL 1024
#define NH 16
#define HD 64

static __device__ __forceinline__ u16 f2bf(float f) {
  union { float f; u32 u; } a; a.f = f;
  u32 r = (a.u + 0x7fffu + ((a.u >> 16) & 1u)) >> 16;
  return (u16)r;
}

static __device__ __forceinline__ f32x4 mfma16(bf16x8 a, bf16x8 b, f32x4 c) {
  return __builtin_amdgcn_mfma_f32_16x16x32_bf16(a, b, c, 0, 0, 0);
}

static __device__ __forceinline__ f32x4 mfma16x16(s16x4 a, s16x4 b, f32x4 c) {
#if __has_builtin(__builtin_amdgcn_mfma_f32_16x16x16bf16_1k)
  return __builtin_amdgcn_mfma_f32_16x16x16bf16_1k(a, b, c, 0, 0, 0);
#else
  asm("v_mfma_f32_16x16x16_bf16 %0, %1, %2, %0" : "+v"(c) : "v"(a), "v"(b));
  return c;
#endif
}

static __device__ __forceinline__ void gload16(const void* g, void* l) {
  __builtin_amdgcn_global_load_lds((const __attribute__((address_space(1))) u32*)g,
                                   (__attribute__((address_space(3))) u32*)l, 16, 0, 0);
}

// counted-vmcnt barrier pair: loads issued for the NEXT tile stay in flight
// across the barrier (only the CURRENT tile's loads are waited on).
#define WAIT_VM(N) asm volatile("s_waitcnt vmcnt(" #N ")" ::: "memory")
static __device__ __forceinline__ void sbar() { __builtin_amdgcn_s_barrier(); }
static __device__ __forceinline__ void spin() { __builtin_amdgcn_sched_barrier(0); }

// bijective chunked XCD swizzle (requires nwg % 8 == 0)
static __device__ __forceinline__ int xcd_swz(int id, int nwg) {
  return (id & 7) * (nwg >> 3) + (id >> 3);
}

// ---------------- fused prep: cast + 4 weight transposes + spec scan ----------------
__global__ __launch_bounds__(256)
void prep_kernel(const float* __restrict__ hidden, const float* __restrict__ Wq,
                 const float* __restrict__ Wk, const float* __restrict__ Wv,
                 const float* __restrict__ Wo, const int* __restrict__ spec,
                 const int* __restrict__ eosi,
                 u16* __restrict__ hbf, u16* __restrict__ wqkvT, u16* __restrict__ woT,
                 u64* __restrict__ spb, int* __restrict__ srank, int4* __restrict__ qmeta) {
  __shared__ float ftile[32][33];
  __shared__ u64 smask[64];
  __shared__ int scnt_s[64];
  __shared__ int spref[64];

  const int bx = (int)blockIdx.x;
  const int t = (int)threadIdx.x;

  if (bx < 4096) {  // cast
    const int i = (bx * 256 + t) * 4;
    const float4 v = *(const float4*)(hidden + i);
    uint2 o;
    o.x = (u32)f2bf(v.x) | ((u32)f2bf(v.y) << 16);
    o.y = (u32)f2bf(v.z) | ((u32)f2bf(v.w) << 16);
    *(uint2*)(hbf + i) = o;
    return;
  }
  if (bx < 6656) {  // weight transposes
    const float* W; u16* WT; int N, loc, nbx;
    if (bx < 5120)      { W = Wq; WT = wqkvT;               N = 1024; loc = bx - 4096; nbx = 32; }
    else if (bx < 5376) { W = Wk; WT = wqkvT + 1024 * 1024; N = 256;  loc = bx - 5120; nbx = 8; }
    else if (bx < 5632) { W = Wv; WT = wqkvT + 1280 * 1024; N = 256;  loc = bx - 5376; nbx = 8; }
    else                { W = Wo; WT = woT;                 N = 1024; loc = bx - 5632; nbx = 32; }
    const int n0 = (loc % nbx) * 32, k0 = (loc / nbx) * 32;
    const int tx = t & 31, ty = t >> 5;
#pragma unroll
    for (int i = 0; i < 4; ++i)
      ftile[ty + 8 * i][tx] = W[(size_t)(k0 + ty + 8 * i) * N + n0 + tx];
    __syncthreads();
#pragma unroll
    for (int i = 0; i < 4; ++i)
      WT[(size_t)(n0 + ty + 8 * i) * 1024 + k0 + tx] = f2bf(ftile[tx][ty + 8 * i]);
    return;
  }
  // spec scan block: bitmasks, per-token spec rank, per-qtile metadata
  const int wv = t >> 6, l = t & 63;
#pragma unroll
  for (int i = 0; i < 16; ++i) {
    const int b = wv * 16 + i;
    const u64 m = __ballot(spec[b * 64 + l] != 0);
    if (l == 0) { smask[b] = m; scnt_s[b] = __popcll(m); }
  }
  __syncthreads();
  if (wv == 0) {
    const int v = scnt_s[l];
    int inc = v;
#pragma unroll
    for (int d = 1; d < 64; d <<= 1) {
      const int o = __shfl_up(inc, d);
      if (l >= d) inc += o;
    }
    spref[l] = inc - v;  // exclusive prefix
    spb[l] = smask[l];
  }
  __syncthreads();
#pragma unroll
  for (int i = 0; i < 16; ++i) {
    const int b = wv * 16 + i;
    const u64 m = smask[b];
    srank[b * 64 + l] = ((m >> l) & 1ull)
        ? spref[b] + __popcll(m & ((1ull << l) - 1ull)) : -1;
  }
  if (t < 64) {
    const int e = eosi[t * 64];
    const int tlo = e >> 6;
    const int nsp = spref[tlo];
    const int nspt = (nsp + 63) >> 6;
    qmeta[t] = make_int4(tlo, nspt, nspt + (t - tlo + 1), nsp);
  }
}

// ---------------- 128x64 MFMA GEMM, BK=64, dbuf + counted-vmcnt (r8 structure) --------
// MODE 0: C fp32 out.  MODE 1: QKV, RoPE fused; K->Kb(+Kg spec), V->Vtg(+Vgt spec).
template <int MODE>
__global__ __launch_bounds__(256, 3)
void gemm128(const u16* __restrict__ A, const u16* __restrict__ BT,
             const float* __restrict__ cosp, const float* __restrict__ sinp,
             const int* __restrict__ srank,
             u16* __restrict__ Qb, u16* __restrict__ Kb, u16* __restrict__ Vtg,
             u16* __restrict__ Kg, u16* __restrict__ Vgt,
             float* __restrict__ Cf) {
  __shared__ __align__(16) u16 As[2][128 * 64];
  __shared__ __align__(16) u16 Bs[2][64 * 64];
  const int t = (int)threadIdx.x;
  const int w = t >> 6;
  const int lane = t & 63;
  const int lr = lane & 15, lg = lane >> 4;

  const int nx = (int)gridDim.x;
  const int nwg = nx * (int)gridDim.y;
  const int id = xcd_swz((int)blockIdx.x + (int)blockIdx.y * nx, nwg);
  const int m0 = (id / nx) * 128;
  const int n0 = (id % nx) * 64;
  const int wm = w * 32;

  f32x4 acc[2][4] = {};

  const int srow = t >> 3;   // 0..31 (per 32-row pass)
  const int sp = t & 7;      // dest 16B chunk within 128B row

  // staging: linear LDS dest (lane-ordered), source chunk pre-swizzled p^(row&7)
  auto STAGE = [&](int buf, int k0) {  // 6 gload16 per thread
#pragma unroll
    for (int i = 0; i < 4; ++i) {
      const int j = i * 32 + srow;
      gload16(A + (size_t)(m0 + j) * 1024 + k0 + ((sp ^ (j & 7)) * 8),
              &As[buf][i * 2048 + t * 8]);
    }
#pragma unroll
    for (int i = 0; i < 2; ++i) {
      const int j = i * 32 + srow;
      gload16(BT + (size_t)(n0 + j) * 1024 + k0 + ((sp ^ (j & 7)) * 8),
              &Bs[buf][i * 2048 + t * 8]);
    }
  };

  STAGE(0, 0);

  for (int it = 0; it < 16; ++it) {
    const int cur = it & 1;
    if (it < 15) {
      STAGE(cur ^ 1, (it + 1) * 64);  // 6 next-tile loads stay in flight
      WAIT_VM(6);                     // only current tile's 6 loads complete
    } else {
      WAIT_VM(0);
    }
    spin();
    sbar();                           // raw barrier: no vmcnt(0) drain
#pragma unroll
    for (int c = 0; c < 2; ++c) {     // k ascending: bit-identical accumulation
      bf16x8 af[2], bg[4];
#pragma unroll
      for (int mi = 0; mi < 2; ++mi) {
        const int row = wm + mi * 16 + lr;
        af[mi] = *(const bf16x8*)&As[cur][row * 64 + (((c * 4 + lg) ^ (row & 7)) * 8)];
      }
#pragma unroll
      for (int ni = 0; ni < 4; ++ni) {
        const int row = ni * 16 + lr;
        bg[ni] = *(const bf16x8*)&Bs[cur][row * 64 + (((c * 4 + lg) ^ (row & 7)) * 8)];
      }
#pragma unroll
      for (int mi = 0; mi < 2; ++mi)
#pragma unroll
        for (int ni = 0; ni < 4; ++ni)
          acc[mi][ni] = mfma16(af[mi], bg[ni], acc[mi][ni]);
    }
    spin();
    sbar();                           // protect cur buffer before next STAGE overwrites
  }

  if (MODE == 0) {
#pragma unroll
    for (int mi = 0; mi < 2; ++mi)
#pragma unroll
      for (int r = 0; r < 4; ++r) {
        const int m = m0 + wm + mi * 16 + lg * 4 + r;
#pragma unroll
        for (int ni = 0; ni < 4; ++ni)
          Cf[(size_t)m * 1024 + n0 + ni * 16 + lr] = acc[mi][ni][r];
      }
  } else if (n0 < 1280) {
    // RoPE (Q or K): pair (d, d+32) = (acc[mi][ni], acc[mi][ni+2])
#pragma unroll
    for (int mi = 0; mi < 2; ++mi)
#pragma unroll
      for (int r = 0; r < 4; ++r) {
        const int m = m0 + wm + mi * 16 + lg * 4 + r;
        const float* cr = cosp + (size_t)m * 64;
        const float* sr = sinp + (size_t)m * 64;
        float o[4];
#pragma unroll
        for (int ni = 0; ni < 2; ++ni) {
          const int d1 = ni * 16 + lr, d2 = d1 + 32;
          const float x = acc[mi][ni][r], y = acc[mi][ni + 2][r];
          o[ni]     = x * cr[d1] - y * sr[d1];
          o[ni + 2] = y * cr[d2] + x * sr[d2];
        }
        if (n0 < 1024) {
          u16* dst = Qb + (size_t)m * 1024 + n0;
#pragma unroll
          for (int ni = 0; ni < 4; ++ni) dst[ni * 16 + lr] = f2bf(o[ni]);
        } else {
          u16 hv[4];
#pragma unroll
          for (int ni = 0; ni < 4; ++ni) hv[ni] = f2bf(o[ni]);
          u16* dst = Kb + (size_t)m * 256 + (n0 - 1024);
          const int sw = (m & 7) << 3;
#pragma unroll
          for (int ni = 0; ni < 4; ++ni) dst[(ni * 16 + lr) ^ sw] = hv[ni];
          const int rk = srank[m];      // fused spec-K gather (same bits as pack did)
          if (rk >= 0) {
            u16* dg = Kg + (size_t)rk * 256 + (n0 - 1024);
            const int swg = (rk & 7) << 3;
#pragma unroll
            for (int ni = 0; ni < 4; ++ni) dg[(ni * 16 + lr) ^ swg] = hv[ni];
          }
        }
      }
  } else {
    // V: transposed + chunk-swizzled into Vtg[kvh*64+d][s]; spec cols also into Vgt
    const int kvh = (n0 - 1280) >> 6;
    int rks[2][4];
#pragma unroll
    for (int mi = 0; mi < 2; ++mi)
#pragma unroll
      for (int r = 0; r < 4; ++r)
        rks[mi][r] = srank[m0 + wm + mi * 16 + lg * 4 + r];
#pragma unroll
    for (int ni = 0; ni < 4; ++ni) {
      const int d = ni * 16 + lr;
      u16* vrow = Vtg + (size_t)(kvh * 64 + d) * 4096;
      u16* grow_ = Vgt + (size_t)(kvh * 64 + d) * 4096;
      const int xd = (d & 7) << 3;
#pragma unroll
      for (int mi = 0; mi < 2; ++mi) {
        const int sb = m0 + wm + mi * 16 + lg * 4;
        const int os = (sb & ~63) | ((sb & 63) ^ xd);
        u16 bv[4];
#pragma unroll
        for (int r = 0; r < 4; ++r) bv[r] = f2bf(acc[mi][ni][r]);
        uint2 pkv;
        pkv.x = (u32)bv[0] | ((u32)bv[1] << 16);
        pkv.y = (u32)bv[2] | ((u32)bv[3] << 16);
        *(uint2*)(vrow + os) = pkv;
#pragma unroll
        for (int r = 0; r < 4; ++r) {   // fused spec-V gather (~5% of rows)
          const int j = rks[mi][r];
          if (j >= 0) grow_[(j & ~63) + ((j & 63) ^ xd)] = bv[r];
        }
      }
    }
  }
}

// ---------------- flash attention, sentence-sparse, counted-vmcnt (r12 + setprio) ----
// grid (64 q-tiles, 16 heads) XCD-swizzled, 256 threads = 4 waves x 16 q-rows
__global__ __launch_bounds__(256, 5)
void attn_kernel(const u16* __restrict__ Qb, const u16* __restrict__ Kb,
                 const u16* __restrict__ Vtg, const u16* __restrict__ Kg,
                 const u16* __restrict__ Vgt, const u64* __restrict__ spb,
                 const int* __restrict__ eosi, const int4* __restrict__ qmeta,
                 u16* __restrict__ Ob) {
  __shared__ __align__(16) u16 lds[2][2][4096];

  const int id = xcd_swz((int)blockIdx.x + (int)blockIdx.y * 64, 1024);
  const int qt = 63 - (id & 63);
  const int h = id >> 6;
  const int kvh = h >> 2;
  const int t = (int)threadIdx.x;
  const int w = t >> 6;
  const int lane = t & 63;
  const int lr = lane & 15, lg = lane >> 4;
  const int q0 = qt * 64;
  const int q = q0 + w * 16 + lr;
  const int swl = (lr & 7) << 3;

  const int4 qm = qmeta[qt];       // {tile_lo, nspt, nit, nsp}
  const int tile_lo = qm.x;
  const int nit = qm.z;
  const int nsp = qm.w;
  const int nloc = qt - tile_lo + 1;

  bf16x8 aq[2];
  {
    const u16* qp = Qb + (size_t)q * 1024 + h * 64 + lg * 8;
    aq[0] = *(const bf16x8*)qp;
    aq[1] = *(const bf16x8*)(qp + 32);
  }
  const int eos_q = eosi[q];

  f32x4 acc[4] = {};
  float mrow = -3.0e38f;
  float lrow = 0.0f;

  const int grow = t >> 3;
  const int gcol = (t & 7) * 8;

  auto STAGE = [&](int buf, int it) {  // 4 gload16 per thread
    const u16 *kp, *vp;
    if (it < nloc) {
      const int kbase = (tile_lo + it) * 64;
      kp = Kb + (size_t)kbase * 256 + kvh * 64;
      vp = Vtg + (size_t)(kvh * 64) * 4096 + kbase;
    } else {
      const int jb = (it - nloc) * 64;
      kp = Kg + (size_t)jb * 256 + kvh * 64;
      vp = Vgt + (size_t)(kvh * 64) * 4096 + jb;
    }
#pragma unroll
    for (int i = 0; i < 2; ++i) {
      gload16(kp + (size_t)(i * 32 + grow) * 256 + gcol, &lds[buf][0][i * 2048 + t * 8]);
      gload16(vp + (size_t)(i * 32 + grow) * 4096 + gcol, &lds[buf][1][i * 2048 + t * 8]);
    }
  };

  STAGE(0, 0);

  for (int it = 0; it < nit; ++it) {
    if (it + 1 < nit) {
      STAGE((it + 1) & 1, it + 1);   // next-tile loads stay in flight
      WAIT_VM(4);
    } else {
      WAIT_VM(0);
    }
    spin();
    sbar();
    const u16* Kl = &lds[it & 1][0][0];
    const u16* Vl = &lds[it & 1][1][0];

    // T5: favor this wave's MFMA cluster over co-resident blocks' staging waves
    __builtin_amdgcn_s_setprio(1);
    f32x4 st[4];
#pragma unroll
    for (int kt = 0; kt < 4; ++kt) {
      f32x4 s = {};
#pragma unroll
      for (int c = 0; c < 2; ++c) {
        bf16x8 ak = *(const bf16x8*)(Kl + (kt * 16 + lr) * 64 + ((c * 32 + lg * 8) ^ swl));
        s = mfma16(ak, aq[c], s);
      }
      st[kt] = s;
    }
    __builtin_amdgcn_s_setprio(0);

    u64 allowed;
    if (it < nloc) {
      const int kbase = (tile_lo + it) * 64;
      const u64 spec = spb[tile_lo + it];
      const int dq = q - kbase;
      const u64 causal = (dq >= 63) ? ~0ull : ((2ull << dq) - 1ull);
      const int de = eos_q - kbase;
      const u64 ge = (de <= 0) ? ~0ull : (de >= 64 ? 0ull : (~0ull << de));
      allowed = causal & (ge | spec);
    } else {
      const int rem = nsp - (it - nloc) * 64;
      allowed = (rem >= 64) ? ~0ull : ((1ull << rem) - 1ull);
    }

    float xs[16];
    float tmax = -3.0e38f;
#pragma unroll
    for (int kt = 0; kt < 4; ++kt) {
      const u32 bits = (u32)(allowed >> (kt * 16 + lg * 4)) & 0xFu;
#pragma unroll
      for (int r = 0; r < 4; ++r) {
        const float x = ((bits >> r) & 1u) ? st[kt][r] * 0.18033688011112042f : -3.0e38f;
        xs[kt * 4 + r] = x;
        tmax = fmaxf(tmax, x);
      }
    }
    tmax = fmaxf(tmax, __shfl_xor(tmax, 16));
    tmax = fmaxf(tmax, __shfl_xor(tmax, 32));
    const float mn = fmaxf(mrow, tmax);
    const float resc = exp2f(mrow - mn);
    mrow = mn;

    float rs = 0.0f;
    u32 pk[8];
#pragma unroll
    for (int i = 0; i < 16; i += 2) {
      const float p0 = exp2f(xs[i] - mn);
      const float p1 = exp2f(xs[i + 1] - mn);
      rs += p0 + p1;
      pk[i >> 1] = (u32)f2bf(p0) | ((u32)f2bf(p1) << 16);
    }
    rs += __shfl_xor(rs, 16);
    rs += __shfl_xor(rs, 32);
    lrow = lrow * resc + rs;

#pragma unroll
    for (int dt = 0; dt < 4; ++dt)
#pragma unroll
      for (int r = 0; r < 4; ++r) acc[dt][r] *= resc;

    __builtin_amdgcn_s_setprio(1);
#pragma unroll
    for (int kt = 0; kt < 4; ++kt) {
      union { u32 u[2]; s16x4 v; } cv;
      cv.u[0] = pk[kt * 2]; cv.u[1] = pk[kt * 2 + 1];
      const int vo = (kt * 16 + lg * 4) ^ swl;
#pragma unroll
      for (int dt = 0; dt < 4; ++dt) {
        s16x4 av = *(const s16x4*)(Vl + (dt * 16 + lr) * 64 + vo);
        acc[dt] = mfma16x16(av, cv.v, acc[dt]);
      }
    }
    __builtin_amdgcn_s_setprio(0);
    spin();
    sbar();
  }

  const float inv = 1.0f / lrow;
#pragma unroll
  for (int dt = 0; dt < 4; ++dt) {
    const u32 w0 = (u32)f2bf(acc[dt][0] * inv) | ((u32)f2bf(acc[dt][1] * inv) << 16);
    const u32 w1 = (u32)f2bf(acc[dt][2] * inv) | ((u32)f2bf(acc[dt][3] * inv) << 16);
    u32* dst = (u32*)(Ob + (size_t)q * 1024 + h * 64 + dt * 16 + lg * 4);
    dst[0] = w0; dst[1] = w1;
  }
}

// ---------------- launch (4 kernels) ----------------
extern "C" void kernel_launch(void* const* d_in, const int* in_sizes, int n_in,
                              void* d_out, int out_size, void* d_ws, size_t ws_size,
                              hipStream_t stream) {
  (void)in_sizes; (void)n_in; (void)out_size; (void)ws_size;
  const float* hidden = (const float*)d_in[0];
  const float* cosp   = (const float*)d_in[1];
  const float* sinp   = (const float*)d_in[2];
  const float* Wq     = (const float*)d_in[3];
  const float* Wk     = (const float*)d_in[4];
  const float* Wv     = (const float*)d_in[5];
  const float* Wo     = (const float*)d_in[6];
  const int* spec     = (const int*)d_in[7];
  const int* eosi     = (const int*)d_in[8];
  float* out = (float*)d_out;

  u16* ws = (u16*)d_ws;
  u16* hbf   = ws;                       // 4096*1024
  u16* wqkvT = hbf + 4194304;            // 1536*1024
  u16* woT   = wqkvT + 1572864;          // 1024*1024
  u16* Qb    = woT + 1048576;            // 4096*1024
  u16* Kb    = Qb + 4194304;             // 4096*256 (chunk-swizzled by row)
  u16* Vtg   = Kb + 1048576;             // 4*64*4096 transposed V (written by gemm<1>)
  u16* Ob    = Vtg + 1048576;            // 4096*1024
  u16* tail  = Ob + 4194304;             // spec metadata
  u64* spb   = (u64*)tail;               // 64 x u64           (tail + 0)
  int* srank = (int*)(tail + 256);       // 4096 int           (tail + 256)
  int4* qmeta = (int4*)(tail + 8448);    // 64 x int4          (tail + 8448)
  u16* Kg    = tail + 8960;              // 4096*256 packed special K (gemm<1>-fused)
  u16* Vgt   = Kg + 1048576;             // 4*64*4096 packed special V^T (gemm<1>-fused)

  prep_kernel<<<dim3(6657), dim3(256), 0, stream>>>(hidden, Wq, Wk, Wv, Wo, spec, eosi,
                                                    hbf, wqkvT, woT, spb, srank, qmeta);
  gemm128<1><<<dim3(24, 32), dim3(256), 0, stream>>>(hbf, wqkvT, cosp, sinp, srank,
                                                     Qb, Kb, Vtg, Kg, Vgt, nullptr);
  attn_kernel<<<dim3(64, 16), dim3(256), 0, stream>>>(Qb, Kb, Vtg, Kg, Vgt, spb,
                                                      eosi, qmeta, Ob);
  gemm128<0><<<dim3(16, 32), dim3(256), 0, stream>>>(Ob, woT, nullptr, nullptr, nullptr,
                                                     nullptr, nullptr, nullptr, nullptr,
                                                     nullptr, out);
}